// Round 3
// baseline (91.662 us; speedup 1.0000x reference)
//
#include <hip/hip_runtime.h>

#define NUM_CLASSES 1024
#define FEAT_DIM    512
#define BATCH       16384
#define ALPHA       0.5f
#define MAXM        128     // max rows per class (Poisson(16), observed max ~35)

// ---- Kernel 1: result[b] = ||features[b] - centers[labels[b]]||^2 ----
// 256 threads = 4 waves; each wave handles 2 rows; grid = BATCH/8 blocks.
// 8 independent float4 loads in flight per wave (feature + gathered center).
__global__ __launch_bounds__(256, 4) void result_kernel(
    const float* __restrict__ features,
    const float* __restrict__ centers,
    const int*   __restrict__ labels,
    float* __restrict__ result)
{
    const int lane = threadIdx.x & 63;
    const int wid  = threadIdx.x >> 6;
    const int row0 = blockIdx.x * 8 + wid * 2;
    const int row1 = row0 + 1;

    const int l0 = labels[row0];
    const int l1 = labels[row1];

    const float4* f0 = (const float4*)(features + (size_t)row0 * FEAT_DIM);
    const float4* f1 = (const float4*)(features + (size_t)row1 * FEAT_DIM);
    const float4* c0 = (const float4*)(centers  + (size_t)l0   * FEAT_DIM);
    const float4* c1 = (const float4*)(centers  + (size_t)l1   * FEAT_DIM);

    const float4 fa0 = f0[lane * 2], fb0 = f0[lane * 2 + 1];
    const float4 fa1 = f1[lane * 2], fb1 = f1[lane * 2 + 1];
    const float4 ca0 = c0[lane * 2], cb0 = c0[lane * 2 + 1];
    const float4 ca1 = c1[lane * 2], cb1 = c1[lane * 2 + 1];

    float d, p0, p1;
    d = fa0.x - ca0.x; p0  = d * d;
    d = fa0.y - ca0.y; p0 += d * d;
    d = fa0.z - ca0.z; p0 += d * d;
    d = fa0.w - ca0.w; p0 += d * d;
    d = fb0.x - cb0.x; p0 += d * d;
    d = fb0.y - cb0.y; p0 += d * d;
    d = fb0.z - cb0.z; p0 += d * d;
    d = fb0.w - cb0.w; p0 += d * d;

    d = fa1.x - ca1.x; p1  = d * d;
    d = fa1.y - ca1.y; p1 += d * d;
    d = fa1.z - ca1.z; p1 += d * d;
    d = fa1.w - ca1.w; p1 += d * d;
    d = fb1.x - cb1.x; p1 += d * d;
    d = fb1.y - cb1.y; p1 += d * d;
    d = fb1.z - cb1.z; p1 += d * d;
    d = fb1.w - cb1.w; p1 += d * d;

    #pragma unroll
    for (int m = 32; m > 0; m >>= 1) {
        p0 += __shfl_xor(p0, m, 64);
        p1 += __shfl_xor(p1, m, 64);
    }
    if (lane == 0) {
        result[row0] = p0;
        result[row1] = p1;
    }
}

// ---- Kernel 2: new_centers[c] = centers[c] - ALPHA*(cnt*centers[c]-fsum[c])/(cnt+1)
// One block per class. Single int4 label scan (L2-served) builds LDS match
// list; then barrier-free block-wide row accumulation (thread owns 2 cols),
// depth-2 software pipelined. Features are L3-resident after kernel 1.
__global__ __launch_bounds__(256, 4) void update_kernel(
    const float* __restrict__ features,
    const float* __restrict__ centers,
    const int*   __restrict__ labels,
    float* __restrict__ new_centers)
{
    const int c   = blockIdx.x;
    const int tid = threadIdx.x;

    __shared__ int match[MAXM];
    __shared__ int nmatch;
    if (tid == 0) nmatch = 0;
    __syncthreads();

    const int4* lab4 = (const int4*)labels;
    #pragma unroll
    for (int i = tid; i < BATCH / 4; i += 256) {
        const int4 L  = lab4[i];
        const int idx = i * 4;
        if (L.x == c) { int p = atomicAdd(&nmatch, 1); if (p < MAXM) match[p] = idx + 0; }
        if (L.y == c) { int p = atomicAdd(&nmatch, 1); if (p < MAXM) match[p] = idx + 1; }
        if (L.z == c) { int p = atomicAdd(&nmatch, 1); if (p < MAXM) match[p] = idx + 2; }
        if (L.w == c) { int p = atomicAdd(&nmatch, 1); if (p < MAXM) match[p] = idx + 3; }
    }
    __syncthreads();

    const int cnt = nmatch;                 // true count (uniform after barrier)
    const int n   = cnt < MAXM ? cnt : MAXM;
    const int col = tid * 2;

    float2 s = make_float2(0.f, 0.f);
    float2 cur;
    if (n > 0)
        cur = *(const float2*)(features + (size_t)match[0] * FEAT_DIM + col);
    for (int r = 1; r < n; ++r) {
        const float2 nxt =
            *(const float2*)(features + (size_t)match[r] * FEAT_DIM + col);
        s.x += cur.x; s.y += cur.y;
        cur = nxt;
    }
    if (n > 0) { s.x += cur.x; s.y += cur.y; }

    const float2 ctr = *(const float2*)(centers + (size_t)c * FEAT_DIM + col);
    const float fc   = (float)cnt;
    const float inv  = 1.0f / (fc + 1.0f);
    float2 o;
    o.x = ctr.x - ALPHA * (fc * ctr.x - s.x) * inv;
    o.y = ctr.y - ALPHA * (fc * ctr.y - s.y) * inv;
    *(float2*)(new_centers + (size_t)c * FEAT_DIM + col) = o;
}

extern "C" void kernel_launch(void* const* d_in, const int* in_sizes, int n_in,
                              void* d_out, int out_size, void* d_ws, size_t ws_size,
                              hipStream_t stream) {
    const float* features = (const float*)d_in[0];   // [BATCH, FEAT_DIM] f32
    const float* centers  = (const float*)d_in[1];   // [NUM_CLASSES, FEAT_DIM] f32
    const int*   labels   = (const int*)d_in[2];     // [BATCH] i32

    float* result      = (float*)d_out;              // [BATCH, 1]
    float* new_centers = (float*)d_out + BATCH;      // [NUM_CLASSES, FEAT_DIM]

    hipLaunchKernelGGL(result_kernel,
                       dim3(BATCH / 8), dim3(256), 0, stream,
                       features, centers, labels, result);
    hipLaunchKernelGGL(update_kernel,
                       dim3(NUM_CLASSES), dim3(256), 0, stream,
                       features, centers, labels, new_centers);
}

// Round 4
// 90.076 us; speedup vs baseline: 1.0176x; 1.0176x over previous
//
#include <hip/hip_runtime.h>

#define NUM_CLASSES 1024
#define FEAT_DIM    512
#define BATCH       16384
#define ALPHA       0.5f
#define MAXM        192          // max rows/class (Poisson(16) max over 1024 ~ 40)
#define RBLOCKS     (BATCH / 8)  // 2048 result-part blocks

// One fused launch, 3072 blocks:
//  blocks [0, 2048):    result[b] = ||features[b]-centers[labels[b]]||^2
//                       (4 waves x 2 rows, 8 float4 loads in flight/wave)
//  blocks [2048, 3072): per-class center update. int4 label scan (L2) ->
//                       LDS match list -> 4-way-MLP row accumulation
//                       (features L3-warm from the result part).
__global__ __launch_bounds__(256, 4) void center_loss_fused(
    const float* __restrict__ features,
    const float* __restrict__ centers,
    const int*   __restrict__ labels,
    float* __restrict__ result,        // [BATCH]
    float* __restrict__ new_centers)   // [NUM_CLASSES * FEAT_DIM]
{
    __shared__ int match[MAXM];
    __shared__ int nmatch;
    const int tid = threadIdx.x;

    if (blockIdx.x < RBLOCKS) {
        // ---------------- result part ----------------
        const int lane = tid & 63;
        const int wid  = tid >> 6;
        const int row0 = blockIdx.x * 8 + wid * 2;
        const int row1 = row0 + 1;

        const int l0 = labels[row0];
        const int l1 = labels[row1];

        const float4* f0 = (const float4*)(features + (size_t)row0 * FEAT_DIM);
        const float4* f1 = (const float4*)(features + (size_t)row1 * FEAT_DIM);
        const float4* c0 = (const float4*)(centers  + (size_t)l0   * FEAT_DIM);
        const float4* c1 = (const float4*)(centers  + (size_t)l1   * FEAT_DIM);

        const float4 fa0 = f0[lane * 2], fb0 = f0[lane * 2 + 1];
        const float4 fa1 = f1[lane * 2], fb1 = f1[lane * 2 + 1];
        const float4 ca0 = c0[lane * 2], cb0 = c0[lane * 2 + 1];
        const float4 ca1 = c1[lane * 2], cb1 = c1[lane * 2 + 1];

        float d, p0, p1;
        d = fa0.x - ca0.x; p0  = d * d;
        d = fa0.y - ca0.y; p0 += d * d;
        d = fa0.z - ca0.z; p0 += d * d;
        d = fa0.w - ca0.w; p0 += d * d;
        d = fb0.x - cb0.x; p0 += d * d;
        d = fb0.y - cb0.y; p0 += d * d;
        d = fb0.z - cb0.z; p0 += d * d;
        d = fb0.w - cb0.w; p0 += d * d;

        d = fa1.x - ca1.x; p1  = d * d;
        d = fa1.y - ca1.y; p1 += d * d;
        d = fa1.z - ca1.z; p1 += d * d;
        d = fa1.w - ca1.w; p1 += d * d;
        d = fb1.x - cb1.x; p1 += d * d;
        d = fb1.y - cb1.y; p1 += d * d;
        d = fb1.z - cb1.z; p1 += d * d;
        d = fb1.w - cb1.w; p1 += d * d;

        #pragma unroll
        for (int m = 32; m > 0; m >>= 1) {
            p0 += __shfl_xor(p0, m, 64);
            p1 += __shfl_xor(p1, m, 64);
        }
        if (lane == 0) {
            result[row0] = p0;
            result[row1] = p1;
        }
        return;
    }

    // ---------------- update part ----------------
    const int c = blockIdx.x - RBLOCKS;

    if (tid == 0) nmatch = 0;
    __syncthreads();

    const int4* lab4 = (const int4*)labels;
    #pragma unroll
    for (int i = tid; i < BATCH / 4; i += 256) {
        const int4 L  = lab4[i];
        const int idx = i * 4;
        if (L.x == c) { int p = atomicAdd(&nmatch, 1); if (p < MAXM) match[p] = idx + 0; }
        if (L.y == c) { int p = atomicAdd(&nmatch, 1); if (p < MAXM) match[p] = idx + 1; }
        if (L.z == c) { int p = atomicAdd(&nmatch, 1); if (p < MAXM) match[p] = idx + 2; }
        if (L.w == c) { int p = atomicAdd(&nmatch, 1); if (p < MAXM) match[p] = idx + 3; }
    }
    __syncthreads();

    const int cnt = nmatch;                 // uniform after barrier
    const int n   = cnt < MAXM ? cnt : MAXM;
    const int col = tid * 2;

    // 4 independent accumulators -> 4 row loads in flight
    float2 s0 = make_float2(0.f, 0.f), s1 = s0, s2 = s0, s3 = s0;
    int r = 0;
    for (; r + 4 <= n; r += 4) {
        const float2 a = *(const float2*)(features + (size_t)match[r+0] * FEAT_DIM + col);
        const float2 b = *(const float2*)(features + (size_t)match[r+1] * FEAT_DIM + col);
        const float2 e = *(const float2*)(features + (size_t)match[r+2] * FEAT_DIM + col);
        const float2 g = *(const float2*)(features + (size_t)match[r+3] * FEAT_DIM + col);
        s0.x += a.x; s0.y += a.y;
        s1.x += b.x; s1.y += b.y;
        s2.x += e.x; s2.y += e.y;
        s3.x += g.x; s3.y += g.y;
    }
    for (; r < n; ++r) {
        const float2 a = *(const float2*)(features + (size_t)match[r] * FEAT_DIM + col);
        s0.x += a.x; s0.y += a.y;
    }
    float2 s;
    s.x = (s0.x + s1.x) + (s2.x + s3.x);
    s.y = (s0.y + s1.y) + (s2.y + s3.y);

    const float2 ctr = *(const float2*)(centers + (size_t)c * FEAT_DIM + col);
    const float fc   = (float)cnt;
    const float inv  = 1.0f / (fc + 1.0f);
    float2 o;
    o.x = ctr.x - ALPHA * (fc * ctr.x - s.x) * inv;
    o.y = ctr.y - ALPHA * (fc * ctr.y - s.y) * inv;
    *(float2*)(new_centers + (size_t)c * FEAT_DIM + col) = o;
}

extern "C" void kernel_launch(void* const* d_in, const int* in_sizes, int n_in,
                              void* d_out, int out_size, void* d_ws, size_t ws_size,
                              hipStream_t stream) {
    const float* features = (const float*)d_in[0];   // [BATCH, FEAT_DIM] f32
    const float* centers  = (const float*)d_in[1];   // [NUM_CLASSES, FEAT_DIM] f32
    const int*   labels   = (const int*)d_in[2];     // [BATCH] i32

    float* result      = (float*)d_out;              // [BATCH, 1]
    float* new_centers = (float*)d_out + BATCH;      // [NUM_CLASSES, FEAT_DIM]

    hipLaunchKernelGGL(center_loss_fused,
                       dim3(RBLOCKS + NUM_CLASSES), dim3(256), 0, stream,
                       features, centers, labels, result, new_centers);
}

// Round 5
// 84.521 us; speedup vs baseline: 1.0845x; 1.0657x over previous
//
#include <hip/hip_runtime.h>

#define NUM_CLASSES 1024
#define FEAT_DIM    512
#define BATCH       16384
#define ALPHA       0.5f
#define MAXM        192     // Poisson(16) max over 1024 classes ~ 45; guarded

// One block (4 waves) per class c. SINGLE pass over features:
//  1) one int4 scan of all 16K labels (L2-served) -> LDS match list (2 barriers)
//  2) rows distributed to waves (r%4); each wave loads the full 512-float row
//     (8 floats/lane), depth-2 software-pipelined (next row's loads in flight
//     during current row's reduce). The same load feeds BOTH the squared
//     distance (-> result[row]) and the per-class feature sum (registers).
//  3) epilogue: combine 4 waves' sums via LDS, write new_centers[c].
__global__ __launch_bounds__(256, 4) void center_loss_kernel(
    const float* __restrict__ features,
    const float* __restrict__ centers,
    const int*   __restrict__ labels,
    float* __restrict__ result,        // [BATCH]
    float* __restrict__ new_centers)   // [NUM_CLASSES * FEAT_DIM]
{
    const int c    = blockIdx.x;
    const int tid  = threadIdx.x;
    const int lane = tid & 63;
    const int wid  = tid >> 6;

    __shared__ int   match[MAXM];
    __shared__ int   nmatch;
    __shared__ float fsum_lds[4 * FEAT_DIM];   // 8 KB

    // center fragment: lane holds cols [lane*8, lane*8+8)
    const float4* cptr = (const float4*)(centers + (size_t)c * FEAT_DIM);
    const float4 ca = cptr[lane * 2 + 0];
    const float4 cb = cptr[lane * 2 + 1];

    if (tid == 0) nmatch = 0;
    __syncthreads();

    // ---- single label scan: 16384 labels as 4096 int4, 16 per thread ----
    const int4* lab4 = (const int4*)labels;
    #pragma unroll
    for (int i = tid; i < BATCH / 4; i += 256) {
        const int4 L  = lab4[i];
        const int idx = i * 4;
        if (L.x == c) { int p = atomicAdd(&nmatch, 1); if (p < MAXM) match[p] = idx + 0; }
        if (L.y == c) { int p = atomicAdd(&nmatch, 1); if (p < MAXM) match[p] = idx + 1; }
        if (L.z == c) { int p = atomicAdd(&nmatch, 1); if (p < MAXM) match[p] = idx + 2; }
        if (L.w == c) { int p = atomicAdd(&nmatch, 1); if (p < MAXM) match[p] = idx + 3; }
    }
    __syncthreads();

    const int cnt = nmatch;                // uniform after barrier
    const int n   = cnt < MAXM ? cnt : MAXM;

    // ---- wave-distributed rows, depth-2 software pipeline ----
    float4 sa = make_float4(0.f, 0.f, 0.f, 0.f);
    float4 sb = make_float4(0.f, 0.f, 0.f, 0.f);

    int r = wid;
    int row = 0;
    float4 fa, fb;
    if (r < n) {
        row = match[r];
        const float4* fp = (const float4*)(features + (size_t)row * FEAT_DIM);
        fa = fp[lane * 2 + 0];
        fb = fp[lane * 2 + 1];
    }
    while (r < n) {
        const int r2 = r + 4;
        int row2 = 0;
        float4 na, nb;
        if (r2 < n) {                       // prefetch next row
            row2 = match[r2];
            const float4* fp = (const float4*)(features + (size_t)row2 * FEAT_DIM);
            na = fp[lane * 2 + 0];
            nb = fp[lane * 2 + 1];
        }

        sa.x += fa.x; sa.y += fa.y; sa.z += fa.z; sa.w += fa.w;
        sb.x += fb.x; sb.y += fb.y; sb.z += fb.z; sb.w += fb.w;

        float d, p;
        d = fa.x - ca.x; p  = d * d;
        d = fa.y - ca.y; p += d * d;
        d = fa.z - ca.z; p += d * d;
        d = fa.w - ca.w; p += d * d;
        d = fb.x - cb.x; p += d * d;
        d = fb.y - cb.y; p += d * d;
        d = fb.z - cb.z; p += d * d;
        d = fb.w - cb.w; p += d * d;

        #pragma unroll
        for (int m = 32; m > 0; m >>= 1)
            p += __shfl_xor(p, m, 64);
        if (lane == 0) result[row] = p;

        r = r2; row = row2; fa = na; fb = nb;
    }

    // ---- epilogue: combine the 4 waves' sums, update centers ----
    __syncthreads();
    float4* dst = (float4*)&fsum_lds[wid * FEAT_DIM + lane * 8];
    dst[0] = sa;
    dst[1] = sb;
    __syncthreads();

    const int j0 = tid * 2;
    float s0 = 0.f, s1 = 0.f;
    #pragma unroll
    for (int w = 0; w < 4; ++w) {
        s0 += fsum_lds[w * FEAT_DIM + j0 + 0];
        s1 += fsum_lds[w * FEAT_DIM + j0 + 1];
    }

    const float2 ctr2 = ((const float2*)(centers + (size_t)c * FEAT_DIM))[tid];
    const float fc  = (float)cnt;
    const float inv = 1.0f / (fc + 1.0f);
    float2 o;
    o.x = ctr2.x - ALPHA * (fc * ctr2.x - s0) * inv;
    o.y = ctr2.y - ALPHA * (fc * ctr2.y - s1) * inv;
    ((float2*)(new_centers + (size_t)c * FEAT_DIM))[tid] = o;
}

extern "C" void kernel_launch(void* const* d_in, const int* in_sizes, int n_in,
                              void* d_out, int out_size, void* d_ws, size_t ws_size,
                              hipStream_t stream) {
    const float* features = (const float*)d_in[0];   // [BATCH, FEAT_DIM] f32
    const float* centers  = (const float*)d_in[1];   // [NUM_CLASSES, FEAT_DIM] f32
    const int*   labels   = (const int*)d_in[2];     // [BATCH] i32

    float* result      = (float*)d_out;              // [BATCH, 1]
    float* new_centers = (float*)d_out + BATCH;      // [NUM_CLASSES, FEAT_DIM]

    hipLaunchKernelGGL(center_loss_kernel,
                       dim3(NUM_CLASSES), dim3(256), 0, stream,
                       features, centers, labels, result, new_centers);
}